// Round 4
// baseline (1577.968 us; speedup 1.0000x reference)
//
#include <hip/hip_runtime.h>

#define Nn 50000
#define Ee 600000
#define Hd 128
#define Ld 4
#define Kd 3

typedef __attribute__((ext_vector_type(8))) short short8;
typedef __attribute__((ext_vector_type(4))) float float4v;

union U4 { uint4 u; short8 s; };

__device__ __forceinline__ unsigned bf16rne(float f) {
    unsigned u = __float_as_uint(f);
    return (u + 0x7fffu + ((u >> 16) & 1u)) >> 16;
}
// split pair of fp32 into packed-bf16 hi dword + lo dword
__device__ __forceinline__ void split2(float f0, float f1, unsigned& hd, unsigned& ld) {
    unsigned h0 = bf16rne(f0), h1 = bf16rne(f1);
    float r0 = f0 - __uint_as_float(h0 << 16);
    float r1 = f1 - __uint_as_float(h1 << 16);
    unsigned l0 = bf16rne(r0), l1 = bf16rne(r1);
    hd = h0 | (h1 << 16);
    ld = l0 | (l1 << 16);
}

__global__ void zero_int_kernel(int* __restrict__ p, int n) {
    int i = blockIdx.x * blockDim.x + threadIdx.x;
    int stride = gridDim.x * blockDim.x;
    for (; i < n; i += stride) p[i] = 0;
}

__global__ void count_kernel(const int* __restrict__ col, int* __restrict__ deg) {
    int e = blockIdx.x * blockDim.x + threadIdx.x;
    if (e < Ee) atomicAdd(&deg[col[e]], 1);
}

// Single-block exclusive scan over deg -> starts[N+1]; also dinv = deg^-1/2.
__global__ void scan_kernel(const int* __restrict__ deg, int* __restrict__ starts,
                            float* __restrict__ dinv) {
    __shared__ int buf[1024];
    __shared__ int carry;
    if (threadIdx.x == 0) carry = 0;
    __syncthreads();
    for (int base = 0; base < Nn; base += 1024) {
        int i = base + threadIdx.x;
        int v = (i < Nn) ? deg[i] : 0;
        if (i < Nn) dinv[i] = (v > 0) ? rsqrtf((float)v) : 0.0f;
        buf[threadIdx.x] = v;
        __syncthreads();
        for (int off = 1; off < 1024; off <<= 1) {
            int t = (threadIdx.x >= off) ? buf[threadIdx.x - off] : 0;
            __syncthreads();
            buf[threadIdx.x] += t;
            __syncthreads();
        }
        if (i < Nn) starts[i] = carry + buf[threadIdx.x] - v;  // exclusive
        __syncthreads();
        if (threadIdx.x == 1023) carry += buf[1023];
        __syncthreads();
    }
    if (threadIdx.x == 0) starts[Nn] = carry;
}

__global__ void fill_kernel(const int* __restrict__ row, const int* __restrict__ col,
                            const int* __restrict__ starts, int* __restrict__ cnt,
                            const float* __restrict__ dinv,
                            int* __restrict__ eid_s, int* __restrict__ src_s,
                            float* __restrict__ w_s) {
    int e = blockIdx.x * blockDim.x + threadIdx.x;
    if (e < Ee) {
        int c = col[e], r = row[e];
        int slot = starts[c] + atomicAdd(&cnt[c], 1);
        eid_s[slot] = e;
        src_s[slot] = r;
        w_s[slot] = dinv[r] * dinv[c];
    }
}

// Convert 17 weight matrices [k][n] fp32 -> transposed planar bf16 hi/lo: WT[m][n][k].
// mat 0 = eW2; mats 1..16 = tagW[l][k] in order.
__global__ void wconv_kernel(const float* __restrict__ eW2, const float* __restrict__ tagW,
                             unsigned short* __restrict__ WThi,
                             unsigned short* __restrict__ WTlo) {
    int id = blockIdx.x * blockDim.x + threadIdx.x;
    if (id >= 17 * 16384) return;
    int m = id >> 14;
    int rem = id & 16383;
    int n = rem >> 7, k = rem & 127;
    const float* src = (m == 0) ? eW2 : tagW + (size_t)(m - 1) * 16384;
    float f = src[k * Hd + n];
    unsigned h = bf16rne(f);
    float r = f - __uint_as_float(h << 16);
    unsigned l = bf16rne(r);
    WThi[id] = (unsigned short)h;
    WTlo[id] = (unsigned short)l;
}

// Layer-1-only edge pass: t[i] = sum over incoming edges of relu(cat(x_i,x_j,e)@W1+b1).
__global__ __launch_bounds__(256) void edge_l1_kernel(
    const float* __restrict__ x, const float* __restrict__ ea,
    const int* __restrict__ starts, const int* __restrict__ eid_s,
    const int* __restrict__ src_s,
    const float* __restrict__ eW1, const float* __restrict__ eb1,
    float* __restrict__ tout) {
    int lane = threadIdx.x & 63;
    float w1x[18], w1y[18];
#pragma unroll
    for (int j = 0; j < 18; ++j) {
        w1x[j] = eW1[j * Hd + lane];
        w1y[j] = eW1[j * Hd + lane + 64];
    }
    float b1x = eb1[lane], b1y = eb1[lane + 64];
    int wid = (blockIdx.x * 256 + threadIdx.x) >> 6;
    int nw = (gridDim.x * 256) >> 6;
    for (int node = wid; node < Nn; node += nw) {
        int s0 = starts[node], s1 = starts[node + 1];
        float prex = b1x, prey = b1y;
#pragma unroll
        for (int j = 0; j < 7; ++j) {
            float xv = x[node * 7 + j];
            prex += xv * w1x[j];
            prey += xv * w1y[j];
        }
        float accx = 0.0f, accy = 0.0f;
        int slot = s0;
        for (; slot + 2 <= s1; slot += 2) {
            int srcA = src_s[slot], srcB = src_s[slot + 1];
            int eA = eid_s[slot], eB = eid_s[slot + 1];
            float4 evA = *(const float4*)&ea[eA * 4];
            float4 evB = *(const float4*)&ea[eB * 4];
            float a0 = prex, a1 = prey, c0 = prex, c1 = prey;
#pragma unroll
            for (int j = 0; j < 7; ++j) {
                float xa = x[srcA * 7 + j];
                float xb = x[srcB * 7 + j];
                a0 += xa * w1x[7 + j];
                a1 += xa * w1y[7 + j];
                c0 += xb * w1x[7 + j];
                c1 += xb * w1y[7 + j];
            }
            a0 += evA.x * w1x[14] + evA.y * w1x[15] + evA.z * w1x[16] + evA.w * w1x[17];
            a1 += evA.x * w1y[14] + evA.y * w1y[15] + evA.z * w1y[16] + evA.w * w1y[17];
            c0 += evB.x * w1x[14] + evB.y * w1x[15] + evB.z * w1x[16] + evB.w * w1x[17];
            c1 += evB.x * w1y[14] + evB.y * w1y[15] + evB.z * w1y[16] + evB.w * w1y[17];
            accx += fmaxf(a0, 0.0f) + fmaxf(c0, 0.0f);
            accy += fmaxf(a1, 0.0f) + fmaxf(c1, 0.0f);
        }
        for (; slot < s1; ++slot) {
            int src = src_s[slot];
            int e = eid_s[slot];
            float a0 = prex, a1 = prey;
#pragma unroll
            for (int j = 0; j < 7; ++j) {
                float xv = x[src * 7 + j];
                a0 += xv * w1x[7 + j];
                a1 += xv * w1y[7 + j];
            }
            float4 ev = *(const float4*)&ea[e * 4];
            a0 += ev.x * w1x[14] + ev.y * w1x[15] + ev.z * w1x[16] + ev.w * w1x[17];
            a1 += ev.x * w1y[14] + ev.y * w1y[15] + ev.z * w1y[16] + ev.w * w1y[17];
            accx += fmaxf(a0, 0.0f);
            accy += fmaxf(a1, 0.0f);
        }
        tout[node * Hd + lane] = accx;
        tout[node * Hd + lane + 64] = accy;
    }
}

// MFMA (split-bf16 x3) multi-source GEMM: C = sum_g Ps[g]@W[g] + bias (+deg*bias).
// Block = 128 threads (2 waves), 64 rows x 128 cols; wave handles 32 rows (2 row-tiles).
// K-chunk = 32 (one mfma_16x16x32 k-step). A fp32 staged to LDS, hi/lo split in-reg.
// W pre-transposed planar bf16 hi/lo [g][n][k] so B-frags are contiguous b128.
__global__ __launch_bounds__(128, 2) void tag_gemm_mfma(
    const float* __restrict__ P0, const float* __restrict__ P1,
    const float* __restrict__ P2, const float* __restrict__ P3,
    const unsigned short* __restrict__ WThi, const unsigned short* __restrict__ WTlo,
    const float* __restrict__ bias, const int* __restrict__ rowdeg,
    float* __restrict__ C, int nsrc, int reluflag) {
    __shared__ float As[64 * 36];            // row stride 36 fp32 (144 B)
    __shared__ unsigned short Ws[128 * 72];  // row: [32 hi][32 lo][8 pad] (144 B)
    const int tid = threadIdx.x;
    const int lane = tid & 63;
    const int wv = tid >> 6;
    const int l15 = lane & 15;
    const int quad = lane >> 4;
    const int rowbase = blockIdx.x * 64;

    float4v acc[2][8];
#pragma unroll
    for (int rt = 0; rt < 2; ++rt)
#pragma unroll
        for (int nt = 0; nt < 8; ++nt) acc[rt][nt] = (float4v)0.0f;

    const float* Ps[4] = {P0, P1, P2, P3};
    const int nchunks = nsrc * 4;

#pragma unroll 1
    for (int chunk = 0; chunk < nchunks; ++chunk) {
        const int g = chunk >> 2;
        const int kb = (chunk & 3) * 32;
        const float* P = Ps[g];
        // stage loads into registers (overlap prev chunk's compute)
        uint4 areg[4], hreg[4], lreg[4];
#pragma unroll
        for (int i = 0; i < 4; ++i) {
            int s = tid + i * 128;             // 0..511
            int r = s >> 3, off = (s & 7) * 4; // A: 64 rows x 32 fp32
            int grow = min(rowbase + r, Nn - 1);
            areg[i] = *(const uint4*)&P[(size_t)grow * Hd + kb + off];
            int n = s >> 2, woff = (s & 3) * 8; // W: 128 rows x 32 bf16
            hreg[i] = *(const uint4*)&WThi[(size_t)g * 16384 + n * Hd + kb + woff];
            lreg[i] = *(const uint4*)&WTlo[(size_t)g * 16384 + n * Hd + kb + woff];
        }
        __syncthreads();
#pragma unroll
        for (int i = 0; i < 4; ++i) {
            int s = tid + i * 128;
            int r = s >> 3, off = (s & 7) * 4;
            *(uint4*)&As[r * 36 + off] = areg[i];
            int n = s >> 2, woff = (s & 3) * 8;
            *(uint4*)&Ws[n * 72 + woff] = hreg[i];
            *(uint4*)&Ws[n * 72 + 32 + woff] = lreg[i];
        }
        __syncthreads();
        // build A hi/lo frags for this wave's 2 row-tiles
        U4 ahi[2], alo[2];
#pragma unroll
        for (int rt = 0; rt < 2; ++rt) {
            int row = wv * 32 + rt * 16 + l15;
            const float* ap = &As[row * 36 + quad * 8];
            float4 fa = *(const float4*)ap;
            float4 fb = *(const float4*)(ap + 4);
            split2(fa.x, fa.y, ahi[rt].u.x, alo[rt].u.x);
            split2(fa.z, fa.w, ahi[rt].u.y, alo[rt].u.y);
            split2(fb.x, fb.y, ahi[rt].u.z, alo[rt].u.z);
            split2(fb.z, fb.w, ahi[rt].u.w, alo[rt].u.w);
        }
#pragma unroll
        for (int nt = 0; nt < 8; ++nt) {
            int wrow = nt * 16 + l15;
            U4 wh, wl;
            wh.u = *(const uint4*)&Ws[wrow * 72 + quad * 8];
            wl.u = *(const uint4*)&Ws[wrow * 72 + 32 + quad * 8];
#pragma unroll
            for (int rt = 0; rt < 2; ++rt) {
                acc[rt][nt] = __builtin_amdgcn_mfma_f32_16x16x32_bf16(ahi[rt].s, wh.s, acc[rt][nt], 0, 0, 0);
                acc[rt][nt] = __builtin_amdgcn_mfma_f32_16x16x32_bf16(alo[rt].s, wh.s, acc[rt][nt], 0, 0, 0);
                acc[rt][nt] = __builtin_amdgcn_mfma_f32_16x16x32_bf16(ahi[rt].s, wl.s, acc[rt][nt], 0, 0, 0);
            }
        }
    }
    // epilogue: C[row][col], row = rowbase + wv*32 + rt*16 + quad*4 + reg, col = nt*16 + l15
#pragma unroll
    for (int rt = 0; rt < 2; ++rt) {
#pragma unroll
        for (int reg = 0; reg < 4; ++reg) {
            int grow = rowbase + wv * 32 + rt * 16 + quad * 4 + reg;
            if (grow < Nn) {
                float bscale = rowdeg ? (float)rowdeg[grow] : 1.0f;
#pragma unroll
                for (int nt = 0; nt < 8; ++nt) {
                    int colg = nt * 16 + l15;
                    float v = acc[rt][nt][reg] + bscale * bias[colg];
                    if (reluflag) v = fmaxf(v, 0.0f);
                    C[(size_t)grow * Hd + colg] = v;
                }
            }
        }
    }
}

// p_out[i] = sum over incoming edges of w[e] * p_in[src[e]]; wave per node.
__global__ void hop_kernel(const float* __restrict__ pin, float* __restrict__ pout,
                           const int* __restrict__ starts, const int* __restrict__ src_s,
                           const float* __restrict__ w_s) {
    int lane = threadIdx.x & 63;
    int wid = (blockIdx.x * blockDim.x + threadIdx.x) >> 6;
    int nw = (gridDim.x * blockDim.x) >> 6;
    for (int node = wid; node < Nn; node += nw) {
        int s0 = starts[node], s1 = starts[node + 1];
        float ax = 0.0f, ay = 0.0f;
        int slot = s0;
        for (; slot + 4 <= s1; slot += 4) {
            int r0 = src_s[slot], r1 = src_s[slot + 1], r2 = src_s[slot + 2], r3 = src_s[slot + 3];
            float w0 = w_s[slot], w1 = w_s[slot + 1], w2v = w_s[slot + 2], w3 = w_s[slot + 3];
            float2 v0 = *(const float2*)&pin[r0 * Hd + 2 * lane];
            float2 v1 = *(const float2*)&pin[r1 * Hd + 2 * lane];
            float2 v2 = *(const float2*)&pin[r2 * Hd + 2 * lane];
            float2 v3 = *(const float2*)&pin[r3 * Hd + 2 * lane];
            ax += w0 * v0.x + w1 * v1.x + w2v * v2.x + w3 * v3.x;
            ay += w0 * v0.y + w1 * v1.y + w2v * v2.y + w3 * v3.y;
        }
        for (; slot < s1; ++slot) {
            int r0 = src_s[slot];
            float w0 = w_s[slot];
            float2 v0 = *(const float2*)&pin[r0 * Hd + 2 * lane];
            ax += w0 * v0.x;
            ay += w0 * v0.y;
        }
        *(float2*)&pout[node * Hd + 2 * lane] = make_float2(ax, ay);
    }
}

__global__ void out_kernel(const float* __restrict__ hin, const float* __restrict__ oW,
                           const float* __restrict__ ob, float* __restrict__ y) {
    __shared__ float w[256];
    __shared__ float bb[2];
    w[threadIdx.x] = oW[threadIdx.x & 255];
    if (threadIdx.x < 2) bb[threadIdx.x] = ob[threadIdx.x];
    __syncthreads();
    int i = blockIdx.x * blockDim.x + threadIdx.x;
    if (i < Nn) {
        float a0 = bb[0], a1 = bb[1];
#pragma unroll
        for (int k = 0; k < Hd; k += 4) {
            float4 hv = *(const float4*)&hin[i * Hd + k];
            a0 += hv.x * w[2 * k] + hv.y * w[2 * k + 2] + hv.z * w[2 * k + 4] + hv.w * w[2 * k + 6];
            a1 += hv.x * w[2 * k + 1] + hv.y * w[2 * k + 3] + hv.z * w[2 * k + 5] + hv.w * w[2 * k + 7];
        }
        *(float2*)&y[i * 2] = make_float2(a0, a1);
    }
}

extern "C" void kernel_launch(void* const* d_in, const int* in_sizes, int n_in,
                              void* d_out, int out_size, void* d_ws, size_t ws_size,
                              hipStream_t stream) {
    const float* x    = (const float*)d_in[0];
    const int*   ei   = (const int*)d_in[1];
    const float* ea   = (const float*)d_in[2];
    const float* eW1  = (const float*)d_in[3];
    const float* eb1  = (const float*)d_in[4];
    const float* eW2  = (const float*)d_in[5];
    const float* eb2  = (const float*)d_in[6];
    const float* tagW = (const float*)d_in[7];
    const float* tagb = (const float*)d_in[8];
    const float* oW   = (const float*)d_in[9];
    const float* ob   = (const float*)d_in[10];
    float* y = (float*)d_out;
    const int* row = ei;        // source
    const int* col = ei + Ee;   // target

    char* wp = (char*)d_ws;
    auto carve = [&](size_t bytes) -> char* {
        char* p = wp;
        wp += (bytes + 15) & ~(size_t)15;
        return p;
    };
    int* deg     = (int*)carve((size_t)2 * Nn * 4);  // deg | cnt adjacent
    int* cnt     = deg + Nn;
    int* starts  = (int*)carve((size_t)(Nn + 1) * 4);
    float* dinv  = (float*)carve((size_t)Nn * 4);
    int* eid_s   = (int*)carve((size_t)Ee * 4);
    int* src_s   = (int*)carve((size_t)Ee * 4);
    float* w_s   = (float*)carve((size_t)Ee * 4);
    unsigned short* WThi = (unsigned short*)carve((size_t)17 * 16384 * 2);
    unsigned short* WTlo = (unsigned short*)carve((size_t)17 * 16384 * 2);
    float* hbuf  = (float*)carve((size_t)Nn * Hd * 4);
    float* obuf  = (float*)carve((size_t)Nn * Hd * 4);
    float* pb0   = (float*)carve((size_t)Nn * Hd * 4);
    float* pb1   = (float*)carve((size_t)Nn * Hd * 4);
    float* pb2   = (float*)carve((size_t)Nn * Hd * 4);

    zero_int_kernel<<<400, 256, 0, stream>>>(deg, 2 * Nn);
    count_kernel<<<(Ee + 255) / 256, 256, 0, stream>>>(col, deg);
    wconv_kernel<<<(17 * 16384 + 255) / 256, 256, 0, stream>>>(eW2, tagW, WThi, WTlo);
    scan_kernel<<<1, 1024, 0, stream>>>(deg, starts, dinv);
    fill_kernel<<<(Ee + 255) / 256, 256, 0, stream>>>(row, col, starts, cnt, dinv,
                                                      eid_s, src_s, w_s);
    // t = per-target sum of relu(layer1)  (into obuf)
    edge_l1_kernel<<<3125, 256, 0, stream>>>(x, ea, starts, eid_s, src_s,
                                             eW1, eb1, obuf);
    // h = t @ W2 + deg*b2  (into hbuf)
    const int gemm_grid = (Nn + 63) / 64;
    tag_gemm_mfma<<<gemm_grid, 128, 0, stream>>>(obuf, nullptr, nullptr, nullptr,
                                                 WThi, WTlo, eb2, deg, hbuf, 1, 0);

    for (int l = 0; l < Ld; ++l) {
        hop_kernel<<<12500, 256, 0, stream>>>(hbuf, pb0, starts, src_s, w_s);
        hop_kernel<<<12500, 256, 0, stream>>>(pb0, pb1, starts, src_s, w_s);
        hop_kernel<<<12500, 256, 0, stream>>>(pb1, pb2, starts, src_s, w_s);
        tag_gemm_mfma<<<gemm_grid, 128, 0, stream>>>(
            hbuf, pb0, pb1, pb2,
            WThi + (size_t)(1 + l * 4) * 16384, WTlo + (size_t)(1 + l * 4) * 16384,
            tagb + l * Hd, nullptr, obuf, 4, (l < Ld - 1) ? 1 : 0);
        float* t = hbuf; hbuf = obuf; obuf = t;
    }
    out_kernel<<<(Nn + 255) / 256, 256, 0, stream>>>(hbuf, oW, ob, y);
}

// Round 5
// 1283.827 us; speedup vs baseline: 1.2291x; 1.2291x over previous
//
#include <hip/hip_runtime.h>

#define Nn 50000
#define Ee 600000
#define Hd 128
#define Ld 4
#define Kd 3

typedef __attribute__((ext_vector_type(8))) short short8;
typedef __attribute__((ext_vector_type(4))) float float4v;

union U4 { uint4 u; short8 s; };

__device__ __forceinline__ unsigned bf16rne(float f) {
    unsigned u = __float_as_uint(f);
    return (u + 0x7fffu + ((u >> 16) & 1u)) >> 16;
}
__device__ __forceinline__ void split2(float f0, float f1, unsigned& hd, unsigned& ld) {
    unsigned h0 = bf16rne(f0), h1 = bf16rne(f1);
    float r0 = f0 - __uint_as_float(h0 << 16);
    float r1 = f1 - __uint_as_float(h1 << 16);
    unsigned l0 = bf16rne(r0), l1 = bf16rne(r1);
    hd = h0 | (h1 << 16);
    ld = l0 | (l1 << 16);
}
__device__ __forceinline__ float bf16lo(unsigned v) { return __uint_as_float(v << 16); }
__device__ __forceinline__ float bf16hi(unsigned v) { return __uint_as_float(v & 0xffff0000u); }

__global__ void zero_int_kernel(int* __restrict__ p, int n) {
    int i = blockIdx.x * blockDim.x + threadIdx.x;
    int stride = gridDim.x * blockDim.x;
    for (; i < n; i += stride) p[i] = 0;
}

__global__ void count_kernel(const int* __restrict__ col, int* __restrict__ deg) {
    int e = blockIdx.x * blockDim.x + threadIdx.x;
    if (e < Ee) atomicAdd(&deg[col[e]], 1);
}

__global__ void scan_kernel(const int* __restrict__ deg, int* __restrict__ starts,
                            float* __restrict__ dinv) {
    __shared__ int buf[1024];
    __shared__ int carry;
    if (threadIdx.x == 0) carry = 0;
    __syncthreads();
    for (int base = 0; base < Nn; base += 1024) {
        int i = base + threadIdx.x;
        int v = (i < Nn) ? deg[i] : 0;
        if (i < Nn) dinv[i] = (v > 0) ? rsqrtf((float)v) : 0.0f;
        buf[threadIdx.x] = v;
        __syncthreads();
        for (int off = 1; off < 1024; off <<= 1) {
            int t = (threadIdx.x >= off) ? buf[threadIdx.x - off] : 0;
            __syncthreads();
            buf[threadIdx.x] += t;
            __syncthreads();
        }
        if (i < Nn) starts[i] = carry + buf[threadIdx.x] - v;
        __syncthreads();
        if (threadIdx.x == 1023) carry += buf[1023];
        __syncthreads();
    }
    if (threadIdx.x == 0) starts[Nn] = carry;
}

__global__ void fill_kernel(const int* __restrict__ row, const int* __restrict__ col,
                            const int* __restrict__ starts, int* __restrict__ cnt,
                            const float* __restrict__ dinv,
                            int* __restrict__ eid_s, int* __restrict__ src_s,
                            float* __restrict__ w_s) {
    int e = blockIdx.x * blockDim.x + threadIdx.x;
    if (e < Ee) {
        int c = col[e], r = row[e];
        int slot = starts[c] + atomicAdd(&cnt[c], 1);
        eid_s[slot] = e;
        src_s[slot] = r;
        w_s[slot] = dinv[r] * dinv[c];
    }
}

// 17 weight matrices [k][n] fp32 -> transposed planar bf16 hi/lo: WT[m][n][k].
__global__ void wconv_kernel(const float* __restrict__ eW2, const float* __restrict__ tagW,
                             unsigned short* __restrict__ WThi,
                             unsigned short* __restrict__ WTlo) {
    int id = blockIdx.x * blockDim.x + threadIdx.x;
    if (id >= 17 * 16384) return;
    int m = id >> 14;
    int rem = id & 16383;
    int n = rem >> 7, k = rem & 127;
    const float* src = (m == 0) ? eW2 : tagW + (size_t)(m - 1) * 16384;
    float f = src[k * Hd + n];
    unsigned h = bf16rne(f);
    float r = f - __uint_as_float(h << 16);
    WThi[id] = (unsigned short)h;
    WTlo[id] = (unsigned short)bf16rne(r);
}

// Layer-1-only edge pass: t[i] = sum over incoming edges of relu(cat(x_i,x_j,e)@W1+b1).
__global__ __launch_bounds__(256) void edge_l1_kernel(
    const float* __restrict__ x, const float* __restrict__ ea,
    const int* __restrict__ starts, const int* __restrict__ eid_s,
    const int* __restrict__ src_s,
    const float* __restrict__ eW1, const float* __restrict__ eb1,
    float* __restrict__ tout) {
    int lane = threadIdx.x & 63;
    float w1x[18], w1y[18];
#pragma unroll
    for (int j = 0; j < 18; ++j) {
        w1x[j] = eW1[j * Hd + lane];
        w1y[j] = eW1[j * Hd + lane + 64];
    }
    float b1x = eb1[lane], b1y = eb1[lane + 64];
    int wid = (blockIdx.x * 256 + threadIdx.x) >> 6;
    int nw = (gridDim.x * 256) >> 6;
    for (int node = wid; node < Nn; node += nw) {
        int s0 = starts[node], s1 = starts[node + 1];
        float prex = b1x, prey = b1y;
#pragma unroll
        for (int j = 0; j < 7; ++j) {
            float xv = x[node * 7 + j];
            prex += xv * w1x[j];
            prey += xv * w1y[j];
        }
        float accx = 0.0f, accy = 0.0f;
        int slot = s0;
        for (; slot + 2 <= s1; slot += 2) {
            int srcA = src_s[slot], srcB = src_s[slot + 1];
            int eA = eid_s[slot], eB = eid_s[slot + 1];
            float4 evA = *(const float4*)&ea[eA * 4];
            float4 evB = *(const float4*)&ea[eB * 4];
            float a0 = prex, a1 = prey, c0 = prex, c1 = prey;
#pragma unroll
            for (int j = 0; j < 7; ++j) {
                float xa = x[srcA * 7 + j];
                float xb = x[srcB * 7 + j];
                a0 += xa * w1x[7 + j];
                a1 += xa * w1y[7 + j];
                c0 += xb * w1x[7 + j];
                c1 += xb * w1y[7 + j];
            }
            a0 += evA.x * w1x[14] + evA.y * w1x[15] + evA.z * w1x[16] + evA.w * w1x[17];
            a1 += evA.x * w1y[14] + evA.y * w1y[15] + evA.z * w1y[16] + evA.w * w1y[17];
            c0 += evB.x * w1x[14] + evB.y * w1x[15] + evB.z * w1x[16] + evB.w * w1x[17];
            c1 += evB.x * w1y[14] + evB.y * w1y[15] + evB.z * w1y[16] + evB.w * w1y[17];
            accx += fmaxf(a0, 0.0f) + fmaxf(c0, 0.0f);
            accy += fmaxf(a1, 0.0f) + fmaxf(c1, 0.0f);
        }
        for (; slot < s1; ++slot) {
            int src = src_s[slot];
            int e = eid_s[slot];
            float a0 = prex, a1 = prey;
#pragma unroll
            for (int j = 0; j < 7; ++j) {
                float xv = x[src * 7 + j];
                a0 += xv * w1x[7 + j];
                a1 += xv * w1y[7 + j];
            }
            float4 ev = *(const float4*)&ea[e * 4];
            a0 += ev.x * w1x[14] + ev.y * w1x[15] + ev.z * w1x[16] + ev.w * w1x[17];
            a1 += ev.x * w1y[14] + ev.y * w1y[15] + ev.z * w1y[16] + ev.w * w1y[17];
            accx += fmaxf(a0, 0.0f);
            accy += fmaxf(a1, 0.0f);
        }
        tout[node * Hd + lane] = accx;
        tout[node * Hd + lane + 64] = accy;
    }
}

// MFMA multi-source GEMM: C = P0@W0 (+ sum_g Pb_g@W_g) + bias (+deg*bias).
// 256 threads / 4 waves; block tile 64 rows x 128 cols; wave = 16 rows.
// g=0: A fp32 (hi/lo split, 3 mfma/k-step). g>=1: A bf16 (2 mfma/k-step).
// Epilogue bounces acc through LDS for coalesced float4 stores (+ bf16 copy).
__global__ __launch_bounds__(256, 2) void tag_gemm_mfma(
    const float* __restrict__ P0,
    const unsigned short* __restrict__ Pb1, const unsigned short* __restrict__ Pb2,
    const unsigned short* __restrict__ Pb3,
    const unsigned short* __restrict__ WThi, const unsigned short* __restrict__ WTlo,
    const float* __restrict__ bias, const int* __restrict__ rowdeg,
    float* __restrict__ C, unsigned short* __restrict__ Cb16,
    int nsrc, int reluflag) {
    __shared__ union {
        struct {
            float As[64 * 36];            // fp32 A tile, stride 36 dw (144 B)
            unsigned short Ab[64 * 40];   // bf16 A tile, stride 40 us (80 B)
            unsigned short Wh[128 * 40];  // W hi plane, stride 40 us
            unsigned short Wl[128 * 40];  // W lo plane
        } a;
        float Cl[64 * 132];               // epilogue bounce, stride 132 dw
    } sm;
    const int tid = threadIdx.x;
    const int lane = tid & 63;
    const int wv = tid >> 6;
    const int l15 = lane & 15;
    const int quad = lane >> 4;
    const int rowbase = blockIdx.x * 64;

    float4v acc[8];
#pragma unroll
    for (int nt = 0; nt < 8; ++nt) acc[nt] = (float4v)0.0f;

    const unsigned short* Pbs[4] = {nullptr, Pb1, Pb2, Pb3};
    const int nchunks = nsrc * 4;

#pragma unroll 1
    for (int chunk = 0; chunk < nchunks; ++chunk) {
        const int g = chunk >> 2;
        const int kb = (chunk & 3) * 32;
        uint4 a4[2], w4[4];
        if (g == 0) {
#pragma unroll
            for (int i = 0; i < 2; ++i) {
                int s = tid + i * 256;
                int r = s >> 3;
                int grow = min(rowbase + r, Nn - 1);
                a4[i] = *(const uint4*)&P0[(size_t)grow * Hd + kb + (s & 7) * 4];
            }
        } else {
            int r = tid >> 2;
            int grow = min(rowbase + r, Nn - 1);
            a4[0] = *(const uint4*)&Pbs[g][(size_t)grow * Hd + kb + (tid & 3) * 8];
        }
#pragma unroll
        for (int i = 0; i < 2; ++i) {
            int s = tid + i * 256;
            int n = s >> 2, off = (s & 3) * 8;
            w4[i]     = *(const uint4*)&WThi[(size_t)g * 16384 + n * Hd + kb + off];
            w4[i + 2] = *(const uint4*)&WTlo[(size_t)g * 16384 + n * Hd + kb + off];
        }
        __syncthreads();
        if (g == 0) {
#pragma unroll
            for (int i = 0; i < 2; ++i) {
                int s = tid + i * 256;
                int r = s >> 3;
                *(uint4*)&sm.a.As[r * 36 + (s & 7) * 4] = a4[i];
            }
        } else {
            int r = tid >> 2;
            *(uint4*)&sm.a.Ab[r * 40 + (tid & 3) * 8] = a4[0];
        }
#pragma unroll
        for (int i = 0; i < 2; ++i) {
            int s = tid + i * 256;
            int n = s >> 2, off = (s & 3) * 8;
            *(uint4*)&sm.a.Wh[n * 40 + off] = w4[i];
            *(uint4*)&sm.a.Wl[n * 40 + off] = w4[i + 2];
        }
        __syncthreads();
        const int arow = wv * 16 + l15;
        U4 ahi, alo, ab;
        if (g == 0) {
            const float* ap = &sm.a.As[arow * 36 + quad * 8];
            float4 fa = *(const float4*)ap;
            float4 fb = *(const float4*)(ap + 4);
            split2(fa.x, fa.y, ahi.u.x, alo.u.x);
            split2(fa.z, fa.w, ahi.u.y, alo.u.y);
            split2(fb.x, fb.y, ahi.u.z, alo.u.z);
            split2(fb.z, fb.w, ahi.u.w, alo.u.w);
        } else {
            ab.u = *(const uint4*)&sm.a.Ab[arow * 40 + quad * 8];
        }
#pragma unroll
        for (int nt = 0; nt < 8; ++nt) {
            int wrow = nt * 16 + l15;
            U4 wh, wl;
            wh.u = *(const uint4*)&sm.a.Wh[wrow * 40 + quad * 8];
            wl.u = *(const uint4*)&sm.a.Wl[wrow * 40 + quad * 8];
            if (g == 0) {
                acc[nt] = __builtin_amdgcn_mfma_f32_16x16x32_bf16(ahi.s, wh.s, acc[nt], 0, 0, 0);
                acc[nt] = __builtin_amdgcn_mfma_f32_16x16x32_bf16(alo.s, wh.s, acc[nt], 0, 0, 0);
                acc[nt] = __builtin_amdgcn_mfma_f32_16x16x32_bf16(ahi.s, wl.s, acc[nt], 0, 0, 0);
            } else {
                acc[nt] = __builtin_amdgcn_mfma_f32_16x16x32_bf16(ab.s, wh.s, acc[nt], 0, 0, 0);
                acc[nt] = __builtin_amdgcn_mfma_f32_16x16x32_bf16(ab.s, wl.s, acc[nt], 0, 0, 0);
            }
        }
    }
    __syncthreads();
    // bounce acc to LDS: row (in-tile) = wv*16 + quad*4 + reg, col = nt*16 + l15
#pragma unroll
    for (int nt = 0; nt < 8; ++nt)
#pragma unroll
        for (int reg = 0; reg < 4; ++reg)
            sm.Cl[(wv * 16 + quad * 4 + reg) * 132 + nt * 16 + l15] = acc[nt][reg];
    __syncthreads();
    // coalesced read-back: 64 rows x 128 cols; 32 threads per row, float4 each
#pragma unroll
    for (int i = 0; i < 8; ++i) {
        int s = tid + i * 256;
        int r = s >> 5, c4 = (s & 31) * 4;
        int grow = rowbase + r;
        if (grow < Nn) {
            float4 v = *(const float4*)&sm.Cl[r * 132 + c4];
            float4 bv = *(const float4*)&bias[c4];
            float bs = rowdeg ? (float)rowdeg[grow] : 1.0f;
            v.x += bs * bv.x; v.y += bs * bv.y; v.z += bs * bv.z; v.w += bs * bv.w;
            if (reluflag) {
                v.x = fmaxf(v.x, 0.0f); v.y = fmaxf(v.y, 0.0f);
                v.z = fmaxf(v.z, 0.0f); v.w = fmaxf(v.w, 0.0f);
            }
            *(float4*)&C[(size_t)grow * Hd + c4] = v;
            if (Cb16) {
                uint2 p;
                p.x = bf16rne(v.x) | (bf16rne(v.y) << 16);
                p.y = bf16rne(v.z) | (bf16rne(v.w) << 16);
                *(uint2*)&Cb16[(size_t)grow * Hd + c4] = p;
            }
        }
    }
}

// bf16 hop: p_out[i] = sum_e w[e] * p_in[src[e]]; fp32 accumulate, bf16 store.
__global__ void hop_kernel(const unsigned short* __restrict__ pin,
                           unsigned short* __restrict__ pout,
                           const int* __restrict__ starts, const int* __restrict__ src_s,
                           const float* __restrict__ w_s) {
    int lane = threadIdx.x & 63;
    int wid = (blockIdx.x * blockDim.x + threadIdx.x) >> 6;
    int nw = (gridDim.x * blockDim.x) >> 6;
    for (int node = wid; node < Nn; node += nw) {
        int s0 = starts[node], s1 = starts[node + 1];
        float ax = 0.0f, ay = 0.0f;
        int slot = s0;
        for (; slot + 4 <= s1; slot += 4) {
            int r0 = src_s[slot], r1 = src_s[slot + 1], r2 = src_s[slot + 2], r3 = src_s[slot + 3];
            float w0 = w_s[slot], w1 = w_s[slot + 1], w2v = w_s[slot + 2], w3 = w_s[slot + 3];
            unsigned v0 = *(const unsigned*)&pin[r0 * Hd + lane * 2];
            unsigned v1 = *(const unsigned*)&pin[r1 * Hd + lane * 2];
            unsigned v2 = *(const unsigned*)&pin[r2 * Hd + lane * 2];
            unsigned v3 = *(const unsigned*)&pin[r3 * Hd + lane * 2];
            ax += w0 * bf16lo(v0) + w1 * bf16lo(v1) + w2v * bf16lo(v2) + w3 * bf16lo(v3);
            ay += w0 * bf16hi(v0) + w1 * bf16hi(v1) + w2v * bf16hi(v2) + w3 * bf16hi(v3);
        }
        for (; slot < s1; ++slot) {
            int r0 = src_s[slot];
            float w0 = w_s[slot];
            unsigned v0 = *(const unsigned*)&pin[r0 * Hd + lane * 2];
            ax += w0 * bf16lo(v0);
            ay += w0 * bf16hi(v0);
        }
        unsigned o = bf16rne(ax) | (bf16rne(ay) << 16);
        *(unsigned*)&pout[node * Hd + lane * 2] = o;
    }
}

__global__ void out_kernel(const float* __restrict__ hin, const float* __restrict__ oW,
                           const float* __restrict__ ob, float* __restrict__ y) {
    __shared__ float w[256];
    __shared__ float bb[2];
    w[threadIdx.x] = oW[threadIdx.x & 255];
    if (threadIdx.x < 2) bb[threadIdx.x] = ob[threadIdx.x];
    __syncthreads();
    int i = blockIdx.x * blockDim.x + threadIdx.x;
    if (i < Nn) {
        float a0 = bb[0], a1 = bb[1];
#pragma unroll
        for (int k = 0; k < Hd; k += 4) {
            float4 hv = *(const float4*)&hin[i * Hd + k];
            a0 += hv.x * w[2 * k] + hv.y * w[2 * k + 2] + hv.z * w[2 * k + 4] + hv.w * w[2 * k + 6];
            a1 += hv.x * w[2 * k + 1] + hv.y * w[2 * k + 3] + hv.z * w[2 * k + 5] + hv.w * w[2 * k + 7];
        }
        *(float2*)&y[i * 2] = make_float2(a0, a1);
    }
}

extern "C" void kernel_launch(void* const* d_in, const int* in_sizes, int n_in,
                              void* d_out, int out_size, void* d_ws, size_t ws_size,
                              hipStream_t stream) {
    const float* x    = (const float*)d_in[0];
    const int*   ei   = (const int*)d_in[1];
    const float* ea   = (const float*)d_in[2];
    const float* eW1  = (const float*)d_in[3];
    const float* eb1  = (const float*)d_in[4];
    const float* eW2  = (const float*)d_in[5];
    const float* eb2  = (const float*)d_in[6];
    const float* tagW = (const float*)d_in[7];
    const float* tagb = (const float*)d_in[8];
    const float* oW   = (const float*)d_in[9];
    const float* ob   = (const float*)d_in[10];
    float* y = (float*)d_out;
    const int* row = ei;        // source
    const int* col = ei + Ee;   // target

    char* wp = (char*)d_ws;
    auto carve = [&](size_t bytes) -> char* {
        char* p = wp;
        wp += (bytes + 15) & ~(size_t)15;
        return p;
    };
    int* deg     = (int*)carve((size_t)2 * Nn * 4);
    int* cnt     = deg + Nn;
    int* starts  = (int*)carve((size_t)(Nn + 1) * 4);
    float* dinv  = (float*)carve((size_t)Nn * 4);
    int* eid_s   = (int*)carve((size_t)Ee * 4);
    int* src_s   = (int*)carve((size_t)Ee * 4);
    float* w_s   = (float*)carve((size_t)Ee * 4);
    unsigned short* WThi = (unsigned short*)carve((size_t)17 * 16384 * 2);
    unsigned short* WTlo = (unsigned short*)carve((size_t)17 * 16384 * 2);
    float* hbuf  = (float*)carve((size_t)Nn * Hd * 4);
    float* obuf  = (float*)carve((size_t)Nn * Hd * 4);
    unsigned short* hb16 = (unsigned short*)carve((size_t)Nn * Hd * 2);
    unsigned short* pb0  = (unsigned short*)carve((size_t)Nn * Hd * 2);
    unsigned short* pb1  = (unsigned short*)carve((size_t)Nn * Hd * 2);
    unsigned short* pb2  = (unsigned short*)carve((size_t)Nn * Hd * 2);

    zero_int_kernel<<<400, 256, 0, stream>>>(deg, 2 * Nn);
    count_kernel<<<(Ee + 255) / 256, 256, 0, stream>>>(col, deg);
    wconv_kernel<<<(17 * 16384 + 255) / 256, 256, 0, stream>>>(eW2, tagW, WThi, WTlo);
    scan_kernel<<<1, 1024, 0, stream>>>(deg, starts, dinv);
    fill_kernel<<<(Ee + 255) / 256, 256, 0, stream>>>(row, col, starts, cnt, dinv,
                                                      eid_s, src_s, w_s);
    // t = per-target sum of relu(layer1)  (into obuf fp32)
    edge_l1_kernel<<<3125, 256, 0, stream>>>(x, ea, starts, eid_s, src_s,
                                             eW1, eb1, obuf);
    // h0 = t @ W2 + deg*b2  (fp32 into hbuf, bf16 copy into hb16)
    const int gemm_grid = (Nn + 63) / 64;
    tag_gemm_mfma<<<gemm_grid, 256, 0, stream>>>(obuf, nullptr, nullptr, nullptr,
                                                 WThi, WTlo, eb2, deg,
                                                 hbuf, hb16, 1, 0);

    for (int l = 0; l < Ld; ++l) {
        hop_kernel<<<12500, 256, 0, stream>>>(hb16, pb0, starts, src_s, w_s);
        hop_kernel<<<12500, 256, 0, stream>>>(pb0, pb1, starts, src_s, w_s);
        hop_kernel<<<12500, 256, 0, stream>>>(pb1, pb2, starts, src_s, w_s);
        tag_gemm_mfma<<<gemm_grid, 256, 0, stream>>>(
            hbuf, pb0, pb1, pb2,
            WThi + (size_t)(1 + l * 4) * 16384, WTlo + (size_t)(1 + l * 4) * 16384,
            tagb + l * Hd, nullptr, obuf,
            (l < Ld - 1) ? hb16 : nullptr, 4, (l < Ld - 1) ? 1 : 0);
        float* t = hbuf; hbuf = obuf; obuf = t;
    }
    out_kernel<<<(Nn + 255) / 256, 256, 0, stream>>>(hbuf, oW, ob, y);
}